// Round 1
// baseline (5995.298 us; speedup 1.0000x reference)
//
#include <hip/hip_runtime.h>
#include <hip/hip_bf16.h>

// HybridQLSTM on MI355X.
// Math: per step t:
//   comb = [x_t, hx]                       [256, 2048]
//   zf   = comb @ (enc_f@Wq)^T + enc_f@bq  [256, 1024]   (encoder folded into weights)
//   zi   = comb @ (enc_i@Wq)^T + enc_i@bq
//   u    = comb @ Wu^T                     (bias bu added in pointwise)
//   o    = comb @ Wo^T                     (bias bo added in pointwise)
//   wires: for w in 0..7: z[:,w] = tanh(z @ w_w[w] + w_b[w])   (sequential, per-row)
//   f = sigmoid(zf), i = sigmoid(zi), g = tanh(u+bu), o = sigmoid(o+bo)
//   cx = f*cx + i*g; hx = o*tanh(cx); outs[t] = hx
// GEMMs in bf16 MFMA (fp32 accumulate); everything else fp32.

#define T_STEPS 128
#define BATCH   256
#define DIN_    1024
#define HID_    1024
#define NQ_     8
#define DCAT    2048   // DIN + HID
#define NG      4096   // [zf | zi | u | o]

using short8 = __attribute__((ext_vector_type(8))) short;
using f32x4  = __attribute__((ext_vector_type(4))) float;

static __device__ __forceinline__ ushort f2bf(float f) {
    union { float f; uint32_t u; } c{f};
    uint32_t u = c.u;
    uint32_t r = (u + 0x7fffu + ((u >> 16) & 1u)) >> 16;   // RNE
    return (ushort)r;
}
static __device__ __forceinline__ float sigmoid_fast(float x) {
    return 1.f / (1.f + __expf(-x));
}
static __device__ __forceinline__ float tanh_fast(float x) {
    float xc = fminf(fmaxf(x, -15.f), 15.f);
    float e  = __expf(-2.f * xc);
    return (1.f - e) / (1.f + e);
}

// ---------------- small precompute kernels ----------------

__global__ void quant_bf16_k(const float* __restrict__ src, ushort* __restrict__ dst, int n4) {
    int i = blockIdx.x * blockDim.x + threadIdx.x;
    if (i < n4) {
        float4 v = ((const float4*)src)[i];
        ushort4 o;
        o.x = f2bf(v.x); o.y = f2bf(v.y); o.z = f2bf(v.z); o.w = f2bf(v.w);
        ((ushort4*)dst)[i] = o;
    }
}

// Wq [1024][2048] fp32 -> WqT [2048][1024] bf16
__global__ void transpose_quant_k(const float* __restrict__ Wq, ushort* __restrict__ WqT) {
    __shared__ float tile[32][33];
    int bx = blockIdx.x;            // along k: 2048/32 = 64
    int by = blockIdx.y;            // along m: 1024/32 = 32
    int tx = threadIdx.x;           // 32
    int ty = threadIdx.y;           // 8
#pragma unroll
    for (int p = 0; p < 4; ++p)
        tile[ty + 8*p][tx] = Wq[(size_t)(by*32 + ty + 8*p) * 2048 + bx*32 + tx];
    __syncthreads();
#pragma unroll
    for (int p = 0; p < 4; ++p)
        WqT[(size_t)(bx*32 + ty + 8*p) * 1024 + by*32 + tx] = f2bf(tile[tx][ty + 8*p]);
}

// bias_out[j] = sum_m enc[j][m] * bq[m]   (fp32, tiny)
__global__ void bias_merge_k(const float* __restrict__ enc, const float* __restrict__ bq,
                             float* __restrict__ out) {
    int j = blockIdx.x * blockDim.x + threadIdx.x;   // 1024 total
    const float* row = enc + (size_t)j * 1024;
    float s = 0.f;
    for (int m = 0; m < 1024; m += 4) {
        float4 e = *(const float4*)(row + m);
        float4 b = *(const float4*)(bq + m);
        s += e.x*b.x + e.y*b.y + e.z*b.z + e.w*b.w;
    }
    out[j] = s;
}

// ---------------- generic bf16 GEMM-BT (for merged weights) ----------------
// C[m][n] = sum_k A[m][k] * Bt[n][k];  A:[M][K] bf16, Bt:[N][K] bf16, C:[M][N] bf16
__global__ __launch_bounds__(256) void gemm_bt_ww_k(const ushort* __restrict__ A,
                                                    const ushort* __restrict__ Bt,
                                                    ushort* __restrict__ C,
                                                    int M, int N, int K) {
    __shared__ ushort As[64][72];
    __shared__ ushort Bs[64][72];
    const int tid = threadIdx.x;
    const int tile_n = blockIdx.x * 64;
    const int tile_m = blockIdx.y * 64;
    const int r8 = tid >> 3;
    const int c8 = (tid & 7) << 3;
    const int wid = tid >> 6, lane = tid & 63;
    const int wm = (wid >> 1) * 32, wn = (wid & 1) * 32;
    const int l15 = lane & 15, lk = (lane >> 4) << 3;

    f32x4 acc00 = {0.f,0.f,0.f,0.f}, acc01 = {0.f,0.f,0.f,0.f};
    f32x4 acc10 = {0.f,0.f,0.f,0.f}, acc11 = {0.f,0.f,0.f,0.f};

    for (int k0 = 0; k0 < K; k0 += 64) {
#pragma unroll
        for (int p = 0; p < 2; ++p) {
            int row = p*32 + r8;
            *(short8*)&As[row][c8] = *(const short8*)(A  + (size_t)(tile_m + row)*K + k0 + c8);
            *(short8*)&Bs[row][c8] = *(const short8*)(Bt + (size_t)(tile_n + row)*K + k0 + c8);
        }
        __syncthreads();
#pragma unroll
        for (int ks = 0; ks < 2; ++ks) {
            short8 a0 = *(short8*)&As[wm      + l15][ks*32 + lk];
            short8 a1 = *(short8*)&As[wm + 16 + l15][ks*32 + lk];
            short8 b0 = *(short8*)&Bs[wn      + l15][ks*32 + lk];
            short8 b1 = *(short8*)&Bs[wn + 16 + l15][ks*32 + lk];
            acc00 = __builtin_amdgcn_mfma_f32_16x16x32_bf16(a0, b0, acc00, 0, 0, 0);
            acc01 = __builtin_amdgcn_mfma_f32_16x16x32_bf16(a0, b1, acc01, 0, 0, 0);
            acc10 = __builtin_amdgcn_mfma_f32_16x16x32_bf16(a1, b0, acc10, 0, 0, 0);
            acc11 = __builtin_amdgcn_mfma_f32_16x16x32_bf16(a1, b1, acc11, 0, 0, 0);
        }
        __syncthreads();
    }
    const int orow = (lane >> 4) * 4;
#pragma unroll
    for (int r = 0; r < 4; ++r) {
        int m0 = tile_m + wm + orow + r;
        int n0 = tile_n + wn + l15;
        C[(size_t)m0*N + n0]           = f2bf(acc00[r]);
        C[(size_t)m0*N + n0 + 16]      = f2bf(acc01[r]);
        C[(size_t)(m0+16)*N + n0]      = f2bf(acc10[r]);
        C[(size_t)(m0+16)*N + n0 + 16] = f2bf(acc11[r]);
    }
}

// ---------------- per-step GEMM ----------------
// preact[b][n] = sum_k comb[b][k] * Wall[n][k]
// comb[b][k] = (k < DIN) ? bf16(x_t[b][k]) : hx_bf[b][k-DIN]
__global__ __launch_bounds__(256) void step_gemm_k(const float* __restrict__ xt,
                                                   const ushort* __restrict__ hxb,
                                                   const ushort* __restrict__ Wall,
                                                   float* __restrict__ preact) {
    __shared__ ushort As[64][72];
    __shared__ ushort Bs[64][72];
    const int tid = threadIdx.x;
    const int tile_n = blockIdx.x * 64;   // 64 tiles
    const int tile_m = blockIdx.y * 64;   // 4 tiles
    const int r8 = tid >> 3;
    const int c8 = (tid & 7) << 3;
    const int wid = tid >> 6, lane = tid & 63;
    const int wm = (wid >> 1) * 32, wn = (wid & 1) * 32;
    const int l15 = lane & 15, lk = (lane >> 4) << 3;

    f32x4 acc00 = {0.f,0.f,0.f,0.f}, acc01 = {0.f,0.f,0.f,0.f};
    f32x4 acc10 = {0.f,0.f,0.f,0.f}, acc11 = {0.f,0.f,0.f,0.f};

    for (int kt = 0; kt < DCAT/64; ++kt) {
        const int k0 = kt * 64;
        if (k0 < DIN_) {
#pragma unroll
            for (int p = 0; p < 2; ++p) {
                int row = p*32 + r8;
                const float* src = xt + (size_t)(tile_m + row)*DIN_ + k0 + c8;
                float4 v0 = *(const float4*)(src);
                float4 v1 = *(const float4*)(src + 4);
                short8 pk;
                pk[0] = (short)f2bf(v0.x); pk[1] = (short)f2bf(v0.y);
                pk[2] = (short)f2bf(v0.z); pk[3] = (short)f2bf(v0.w);
                pk[4] = (short)f2bf(v1.x); pk[5] = (short)f2bf(v1.y);
                pk[6] = (short)f2bf(v1.z); pk[7] = (short)f2bf(v1.w);
                *(short8*)&As[row][c8] = pk;
            }
        } else {
#pragma unroll
            for (int p = 0; p < 2; ++p) {
                int row = p*32 + r8;
                *(short8*)&As[row][c8] =
                    *(const short8*)(hxb + (size_t)(tile_m + row)*HID_ + (k0 - DIN_) + c8);
            }
        }
#pragma unroll
        for (int p = 0; p < 2; ++p) {
            int row = p*32 + r8;
            *(short8*)&Bs[row][c8] =
                *(const short8*)(Wall + (size_t)(tile_n + row)*DCAT + k0 + c8);
        }
        __syncthreads();
#pragma unroll
        for (int ks = 0; ks < 2; ++ks) {
            short8 a0 = *(short8*)&As[wm      + l15][ks*32 + lk];
            short8 a1 = *(short8*)&As[wm + 16 + l15][ks*32 + lk];
            short8 b0 = *(short8*)&Bs[wn      + l15][ks*32 + lk];
            short8 b1 = *(short8*)&Bs[wn + 16 + l15][ks*32 + lk];
            acc00 = __builtin_amdgcn_mfma_f32_16x16x32_bf16(a0, b0, acc00, 0, 0, 0);
            acc01 = __builtin_amdgcn_mfma_f32_16x16x32_bf16(a0, b1, acc01, 0, 0, 0);
            acc10 = __builtin_amdgcn_mfma_f32_16x16x32_bf16(a1, b0, acc10, 0, 0, 0);
            acc11 = __builtin_amdgcn_mfma_f32_16x16x32_bf16(a1, b1, acc11, 0, 0, 0);
        }
        __syncthreads();
    }
    const int orow = (lane >> 4) * 4;
#pragma unroll
    for (int r = 0; r < 4; ++r) {
        int m0 = tile_m + wm + orow + r;
        int n0 = tile_n + wn + l15;
        preact[(size_t)m0*NG + n0]           = acc00[r];
        preact[(size_t)m0*NG + n0 + 16]      = acc01[r];
        preact[(size_t)(m0+16)*NG + n0]      = acc10[r];
        preact[(size_t)(m0+16)*NG + n0 + 16] = acc11[r];
    }
}

// ---------------- per-step pointwise: wires + gates + state ----------------
// grid = 256 (one block per batch row), block = 128 (wave0: f-gate, wave1: i-gate)
__global__ __launch_bounds__(128) void step_pointwise_k(
        const float* __restrict__ preact,
        const float* __restrict__ wfw, const float* __restrict__ wfb,
        const float* __restrict__ wiw, const float* __restrict__ wib,
        const float* __restrict__ bu,  const float* __restrict__ bo,
        const float* __restrict__ bias_zf, const float* __restrict__ bias_zi,
        float* __restrict__ cx, ushort* __restrict__ hxb,
        float* __restrict__ dout, int t) {
    __shared__ float zrow[2][1024];
    const int b = blockIdx.x;
    const int tid = threadIdx.x;
    const int wid = tid >> 6;        // 0: f, 1: i
    const int lane = tid & 63;

    const float* pre  = preact + (size_t)b*NG + wid*HID_;
    const float* bias = wid == 0 ? bias_zf : bias_zi;
    const float* ww   = wid == 0 ? wfw : wiw;
    const float* wb   = wid == 0 ? wfb : wib;

    float z[16];
#pragma unroll
    for (int j = 0; j < 16; ++j) z[j] = pre[j*64 + lane] + bias[j*64 + lane];

    // sequential wires: z[w] = tanh(dot(z, ww[w]) + wb[w]), w = 0..7 (element w lives on lane w, j=0)
#pragma unroll
    for (int w = 0; w < NQ_; ++w) {
        float p = 0.f;
#pragma unroll
        for (int j = 0; j < 16; ++j) p += z[j] * ww[(size_t)w*1024 + j*64 + lane];
#pragma unroll
        for (int off = 1; off < 64; off <<= 1) p += __shfl_xor(p, off, 64);
        float s = tanh_fast(p + wb[w]);
        if (lane == w) z[0] = s;
    }
#pragma unroll
    for (int j = 0; j < 16; ++j) zrow[wid][j*64 + lane] = z[j];
    __syncthreads();

    const float* prow = preact + (size_t)b*NG;
#pragma unroll
    for (int e = 0; e < 8; ++e) {
        int k = e*128 + tid;
        float f  = sigmoid_fast(zrow[0][k]);
        float ig = sigmoid_fast(zrow[1][k]);
        float g  = tanh_fast(prow[2048 + k] + bu[k]);
        float o  = sigmoid_fast(prow[3072 + k] + bo[k]);
        float c  = f * cx[(size_t)b*HID_ + k] + ig * g;
        cx[(size_t)b*HID_ + k] = c;
        float h  = o * tanh_fast(c);
        dout[(size_t)t*BATCH*HID_ + (size_t)b*HID_ + k] = h;
        hxb[(size_t)b*HID_ + k] = f2bf(h);
        if (t == T_STEPS - 1) {
            dout[(size_t)T_STEPS*BATCH*HID_ + (size_t)b*HID_ + k] = h;
            dout[(size_t)T_STEPS*BATCH*HID_ + (size_t)BATCH*HID_ + (size_t)b*HID_ + k] = c;
        }
    }
}

// ---------------- launch ----------------
extern "C" void kernel_launch(void* const* d_in, const int* in_sizes, int n_in,
                              void* d_out, int out_size, void* d_ws, size_t ws_size,
                              hipStream_t stream) {
    const float* inputs = (const float*)d_in[0];
    const float* Wq     = (const float*)d_in[1];
    const float* bq     = (const float*)d_in[2];
    const float* enc_f  = (const float*)d_in[3];
    const float* wf_w   = (const float*)d_in[4];
    const float* wf_b   = (const float*)d_in[5];
    const float* enc_i  = (const float*)d_in[6];
    const float* wi_w   = (const float*)d_in[7];
    const float* wi_b   = (const float*)d_in[8];
    const float* Wu     = (const float*)d_in[9];
    const float* bu     = (const float*)d_in[10];
    const float* Wo     = (const float*)d_in[11];
    const float* bo     = (const float*)d_in[12];
    float* out = (float*)d_out;

    char* ws = (char*)d_ws;
    // ws layout (bytes):
    ushort* Wall    = (ushort*)(ws);                          // [4096][2048] bf16 = 16 MiB
    ushort* WqT     = (ushort*)(ws + (16u<<20));              // [2048][1024] bf16 = 4 MiB
    ushort* encfb   = (ushort*)(ws + (20u<<20));              // [1024][1024] bf16 = 2 MiB
    ushort* encib   = (ushort*)(ws + (22u<<20));              // 2 MiB
    float*  preact  = (float*) (ws + (24u<<20));              // [256][4096] f32 = 4 MiB
    float*  cx      = (float*) (ws + (28u<<20));              // [256][1024] f32 = 1 MiB
    ushort* hxb     = (ushort*)(ws + (29u<<20));              // [256][1024] bf16 = 0.5 MiB
    float*  bias_zf = (float*) (ws + (30u<<20));              // 4 KiB
    float*  bias_zi = (float*) (ws + (30u<<20) + 4096);       // 4 KiB
    // total ~30.1 MiB

    // init state
    hipMemsetAsync(cx,  0, (size_t)BATCH*HID_*sizeof(float), stream);
    hipMemsetAsync(hxb, 0, (size_t)BATCH*HID_*sizeof(ushort), stream);

    // quantize weights
    quant_bf16_k<<<(1024*1024/4 + 255)/256, 256, 0, stream>>>(enc_f, encfb, 1024*1024/4);
    quant_bf16_k<<<(1024*1024/4 + 255)/256, 256, 0, stream>>>(enc_i, encib, 1024*1024/4);
    quant_bf16_k<<<(1024*2048/4 + 255)/256, 256, 0, stream>>>(Wu, Wall + (size_t)2048*2048, 1024*2048/4);
    quant_bf16_k<<<(1024*2048/4 + 255)/256, 256, 0, stream>>>(Wo, Wall + (size_t)3072*2048, 1024*2048/4);
    transpose_quant_k<<<dim3(64, 32), dim3(32, 8), 0, stream>>>(Wq, WqT);
    bias_merge_k<<<4, 256, 0, stream>>>(enc_f, bq, bias_zf);
    bias_merge_k<<<4, 256, 0, stream>>>(enc_i, bq, bias_zi);

    // merged encoder weights: Wall rows 0..1023 = enc_f@Wq, rows 1024..2047 = enc_i@Wq
    gemm_bt_ww_k<<<dim3(2048/64, 1024/64), 256, 0, stream>>>(encfb, WqT, Wall, 1024, 2048, 1024);
    gemm_bt_ww_k<<<dim3(2048/64, 1024/64), 256, 0, stream>>>(encib, WqT, Wall + (size_t)1024*2048, 1024, 2048, 1024);

    // recurrent loop
    for (int t = 0; t < T_STEPS; ++t) {
        step_gemm_k<<<dim3(NG/64, BATCH/64), 256, 0, stream>>>(
            inputs + (size_t)t*BATCH*DIN_, hxb, Wall, preact);
        step_pointwise_k<<<256, 128, 0, stream>>>(
            preact, wf_w, wf_b, wi_w, wi_b, bu, bo, bias_zf, bias_zi,
            cx, hxb, out, t);
    }
}